// Round 8
// baseline (179.924 us; speedup 1.0000x reference)
//
#include <hip/hip_runtime.h>

#define NG 12
#define SD 64
#define ED 768
#define NB 262144
#define TPB 384          // 6 waves; thread t owns output cols [2t, 2t+2)
#define G   2048         // grid size; ITERS grid-stride iterations per block
#define ITERS (NB / G)   // 128

typedef float f32x2 __attribute__((ext_vector_type(2)));  // native vec for nt-store

// M[g][o] = sum_s Wg[g][s] * Wagg[o][g*64+s];  Mb[g][o] = same with bg
__global__ void fge_pre1(const float* __restrict__ Wg,
                         const float* __restrict__ bg,
                         const float* __restrict__ Wagg,
                         float* __restrict__ M, float* __restrict__ Mb)
{
    int tid = blockIdx.x * blockDim.x + threadIdx.x;
    if (tid >= ED * NG) return;
    int o = tid / NG, g = tid % NG;   // 12 consecutive threads share one Wagg row
    const float* wrow = Wagg + (size_t)o * ED + g * SD;
    const float* wgp  = Wg + g * SD;
    const float* bgp  = bg + g * SD;
    float m = 0.f, mb = 0.f;
    #pragma unroll
    for (int s = 0; s < SD; ++s) {
        float w = wrow[s];
        m  += wgp[s] * w;
        mb += bgp[s] * w;
    }
    M [g * ED + o] = m;
    Mb[g * ED + o] = mb;
}

// c0[o] = bagg[o] + sum_g Mb[g][o]
__global__ void fge_pre2(const float* __restrict__ Mb,
                         const float* __restrict__ bagg,
                         float* __restrict__ c0)
{
    int o = blockIdx.x * blockDim.x + threadIdx.x;
    if (o >= ED) return;
    float s = bagg[o];
    #pragma unroll
    for (int g = 0; g < NG; ++g) s += Mb[g * ED + o];
    c0[o] = s;
}

// cvt counts (SGPR-resident) -> per-lane floats, BEFORE next prefetch issues
__device__ __forceinline__ void cvt12(int4 x, int4 y, int4 z, float (&cf)[NG]) {
    cf[0]=(float)x.x; cf[1]=(float)x.y; cf[2] =(float)x.z; cf[3] =(float)x.w;
    cf[4]=(float)y.x; cf[5]=(float)y.y; cf[6] =(float)y.z; cf[7] =(float)y.w;
    cf[8]=(float)z.x; cf[9]=(float)z.y; cf[10]=(float)z.z; cf[11]=(float)z.w;
}

__device__ __forceinline__ void row_fma_store(const float (&cf)[NG],
                                              const float (&m)[NG][2],
                                              float bx, float by,
                                              float* __restrict__ dst)
{
    float a0 = bx, a1 = by;
    #pragma unroll
    for (int g = 0; g < NG; ++g) {
        a0 = fmaf(cf[g], m[g][0], a0);
        a1 = fmaf(cf[g], m[g][1], a1);
    }
    f32x2 v = { a0, a1 };
    // nt store: LLC no-allocate, keeps L2 clean (round 6: -25%)
    __builtin_nontemporal_store(v, reinterpret_cast<f32x2*>(dst));
}

// out[b][o] = c0[o] + sum_g counts[b][g] * M[g][o]
// 2 cols/thread -> ~50 VGPRs -> 8 waves/SIMD (30 waves/CU).
// Per 2-row group: cvt row A -> issue A-prefetch -> FMA+store A -> cvt B ->
// issue B-prefetch -> FMA+store B. lgkm waits sit ~2 rows from their loads.
__global__ __launch_bounds__(TPB, 8) void fge_main(const int* __restrict__ counts,
                                                   const float* __restrict__ M,
                                                   const float* __restrict__ c0,
                                                   float* __restrict__ out)
{
    const int t  = threadIdx.x;
    const int o0 = t * 2;

    float m[NG][2];
    #pragma unroll
    for (int g = 0; g < NG; ++g) {
        m[g][0] = M[g * ED + o0];
        m[g][1] = M[g * ED + o0 + 1];
    }
    const float bx = c0[o0], by = c0[o0 + 1];

    const int4* cp = reinterpret_cast<const int4*>(counts);  // 3 int4 per row

    int b = blockIdx.x;
    int4 A0 = cp[b * 3], A1 = cp[b * 3 + 1], A2 = cp[b * 3 + 2];
    int r1 = b + G;
    int4 B0 = cp[r1 * 3], B1 = cp[r1 * 3 + 1], B2 = cp[r1 * 3 + 2];

    #pragma unroll 1
    for (int i = 0; i < ITERS; i += 2) {
        float cfA[NG], cfB[NG];

        cvt12(A0, A1, A2, cfA);                        // consume A's SGPRs
        int pa = b + 2 * G; pa = pa < NB ? pa : NB - 1;
        A0 = cp[pa * 3]; A1 = cp[pa * 3 + 1]; A2 = cp[pa * 3 + 2];
        row_fma_store(cfA, m, bx, by, out + (size_t)b * ED + o0);

        cvt12(B0, B1, B2, cfB);                        // consume B's SGPRs
        int pb = b + 3 * G; pb = pb < NB ? pb : NB - 1;
        B0 = cp[pb * 3]; B1 = cp[pb * 3 + 1]; B2 = cp[pb * 3 + 2];
        row_fma_store(cfB, m, bx, by, out + (size_t)(b + G) * ED + o0);

        b += 2 * G;
    }
}

extern "C" void kernel_launch(void* const* d_in, const int* in_sizes, int n_in,
                              void* d_out, int out_size, void* d_ws, size_t ws_size,
                              hipStream_t stream) {
    const int*   counts = (const int*)  d_in[0];
    const float* Wg     = (const float*)d_in[1];
    const float* bg     = (const float*)d_in[2];
    const float* Wagg   = (const float*)d_in[3];
    const float* bagg   = (const float*)d_in[4];
    float* out = (float*)d_out;

    float* M  = (float*)d_ws;            // 12*768 = 36 KB
    float* Mb = M  + NG * ED;            // 36 KB
    float* c0 = Mb + NG * ED;            // 3 KB

    fge_pre1<<<(ED * NG + 255) / 256, 256, 0, stream>>>(Wg, bg, Wagg, M, Mb);
    fge_pre2<<<(ED + 255) / 256, 256, 0, stream>>>(Mb, bagg, c0);
    fge_main<<<G, TPB, 0, stream>>>(counts, M, c0, out);
}